// Round 1
// baseline (163.874 us; speedup 1.0000x reference)
//
#include <hip/hip_runtime.h>

// Balloon-Windkessel BOLD, explicit Euler, T=1000, B=16384.
// alpha==1 decouples the system: (s,f) is an affine scan with constant 2x2
// matrix A; v,q are affine scans with constant scalar av = 1-DT/lamb. Only
// E(f) is nonlinear (pointwise). Parallelize T:
//   40 chunks x 25 steps; block = 16 sims x 40 chunks = 640 threads.
//   P1: load chunk z into 25 REGISTERS (one pass over noise, NT loads),
//       per-chunk (s,f) affine aggregate
//   scan1 (LDS, Hillis-Steele, weights A^(25*2^j), 6 levels) -> chunk (s,f)
//   P2: replay (s,f) from registered z; accumulate v,q aggregates;
//       OVERWRITE each z register with that step's f (z dead after use)
//   scan2 (scalar av^(25*2^j)) -> chunk-start (v,q)
//   P3: consume registered f directly (no noise reload, no (s,f) replay),
//       compute y, NT store.
// vs the 20x50 version: noise is read ONCE from HBM instead of 3x
// (95 MB -> ~66 MB fetch), P3 drops the whole (s,f) replay, and the
// chunk-power matrices (f64, computed once) keep chunk-start rounding ~1e-6.
// f bits in P3 are identical to P2's by construction (stored, not replayed).

#define BATCH     16384
#define DT        0.01f
#define NOISE_AMP 0.01f
#define V0        0.02f
#define CHUNKS    40
#define CL        25          // 40 * 25 = 1000 steps
#define GSIMS     16
#define NTHREADS  (CHUNKS * GSIMS)   // 640
#define LEVELS    6           // ceil(log2(40))

#if __has_builtin(__builtin_amdgcn_exp2f)
#define EXP2F(x) __builtin_amdgcn_exp2f(x)
#else
#define EXP2F(x) exp2f(x)
#endif

__device__ __forceinline__ float uf(float x) {
    return __uint_as_float(__builtin_amdgcn_readfirstlane(__float_as_uint(x)));
}

struct D22 { double a, b, c, d; };
__device__ __forceinline__ D22 dmul(D22 x, D22 y) {
    D22 r;
    r.a = x.a * y.a + x.b * y.c;  r.b = x.a * y.b + x.b * y.d;
    r.c = x.c * y.a + x.d * y.c;  r.d = x.c * y.b + x.d * y.d;
    return r;
}

// launch_bounds(640, 6): cap VGPR at 85 (no spills); if allocator lands
// <=64 we get 3 blocks/CU (30 waves), else 2 blocks/CU (20 waves, = old).
__global__ __launch_bounds__(NTHREADS, 6) void balloon_scan(
    const float* __restrict__ noise,
    const float* __restrict__ p_sigma,
    const float* __restrict__ p_mu,
    const float* __restrict__ p_lamb,
    const float* __restrict__ p_beta,
    const float* __restrict__ p_psi,
    const float* __restrict__ p_phi,
    const float* __restrict__ p_chi,
    float* __restrict__ out)
{
    const int tid = threadIdx.x;
    const int g   = tid & (GSIMS - 1);   // sim within block
    const int cc  = tid >> 4;            // chunk 0..39
    const int sim = blockIdx.x * GSIMS + g;

    const float sigma = uf(p_sigma[0]);
    const float mu    = uf(p_mu[0]);
    const float lamb  = uf(p_lamb[0]);
    const float beta  = uf(p_beta[0]);
    const float psi   = uf(p_psi[0]);
    const float phi   = uf(p_phi[0]);
    const float chi   = uf(p_chi[0]);

    // ---- uniform fp32 step constants (identical forms to the validated R2) ----
    const float as_   = 1.0f - DT * sigma;
    const float dtn   = DT * NOISE_AMP;
    const float dtm   = DT * mu;
    const float dt_il = uf((float)(0.01 / (double)lamb));
    const float av    = 1.0f - dt_il;
    const float kq    = uf(dt_il / beta);
    const float lc    = uf(log2f(1.0f - beta));
    const float c0 = V0 * (phi + psi + chi), c1 = V0 * phi, c2 = V0 * psi, c3 = V0 * chi;

    // ---- chunk-power weights in f64, once: A^(25*2^j), av^(25*2^j) ----
    D22 A; A.a = 1.0 - 0.01 * (double)sigma; A.b = -0.01 * (double)mu;
           A.c = 0.01;                       A.d = 1.0;
    D22 A2 = dmul(A, A), A4 = dmul(A2, A2), A8 = dmul(A4, A4);
    D22 A16 = dmul(A8, A8);
    D22 P = dmul(dmul(A16, A8), A);                 // A^25 = A^16*A^8*A^1
    double avd = 1.0 - 0.01 / (double)lamb;
    double av2 = avd * avd, av4 = av2 * av2, av8 = av4 * av4;
    double av16 = av8 * av8;
    double ap = av16 * av8 * avd;                   // av^25

    float M11[LEVELS], M12[LEVELS], M21[LEVELS], M22[LEVELS], AVP[LEVELS];
#pragma unroll
    for (int j = 0; j < LEVELS; ++j) {
        M11[j] = uf((float)P.a); M12[j] = uf((float)P.b);
        M21[j] = uf((float)P.c); M22[j] = uf((float)P.d);
        AVP[j] = uf((float)ap);
        P = dmul(P, P); ap = ap * ap;
    }

    // homogeneous parts at this thread's chunk start: A^(25c)*(0,1), av^(25c)*1
    float ws = 0.0f, wf = 1.0f, avc = 1.0f;
#pragma unroll
    for (int j = 0; j < LEVELS; ++j) {
        if ((cc >> j) & 1) {
            float t = __builtin_fmaf(M11[j], ws, M12[j] * wf);
            wf = __builtin_fmaf(M21[j], ws, M22[j] * wf);
            ws = t;
            avc *= AVP[j];
        }
    }

    __shared__ float sA[NTHREADS];
    __shared__ float sB[NTHREADS];

    const float* zp = noise + cc * (CL * BATCH) + sim;

    // ---------------- P1: load z once into registers; (s,f) aggregate ----------------
    float zr[CL];
#pragma unroll
    for (int j = 0; j < CL; ++j)
        zr[j] = __builtin_nontemporal_load(&zp[j * BATCH]);

    float rs = 0.0f, rf = 0.0f;
#pragma unroll
    for (int j = 0; j < CL; ++j) {
        const float u = __builtin_fmaf(dtn, zr[j], dtm);
        const float t = __builtin_fmaf(as_, rs, __builtin_fmaf(-dtm, rf, u));
        rf = __builtin_fmaf(DT, rs, rf);
        rs = t;
    }

    // ---------------- scan1: inclusive over chunks, matrix weights ----------------
    sA[tid] = rs; sB[tid] = rf;
    __syncthreads();
#pragma unroll
    for (int j = 0; j < LEVELS; ++j) {
        const int off = 1 << j;
        float ns = 0.0f, nf = 0.0f;
        const bool has = (cc >= off);
        if (has) { ns = sA[tid - off * GSIMS]; nf = sB[tid - off * GSIMS]; }
        __syncthreads();
        if (has) {
            rs = __builtin_fmaf(M11[j], ns, __builtin_fmaf(M12[j], nf, rs));
            rf = __builtin_fmaf(M21[j], ns, __builtin_fmaf(M22[j], nf, rf));
            sA[tid] = rs; sB[tid] = rf;
        }
        __syncthreads();
    }
    float s0 = ws, f0 = wf;
    if (cc > 0) { s0 += sA[tid - GSIMS]; f0 += sB[tid - GSIMS]; }
    __syncthreads();   // sA/sB reads done; safe to reuse for scan2

    // ---------------- P2: replay (s,f) from regs; v,q aggregates; stash f ----------------
    float s = s0, f = f0, Rv = 0.0f, Rq = 0.0f;
#pragma unroll
    for (int j = 0; j < CL; ++j) {
        const float zf   = zr[j];
        const float invf = __builtin_amdgcn_rcpf(f);
        const float e2   = EXP2F(lc * invf);
        const float t1   = __builtin_fmaf(-f, e2, f);       // f*E(f)
        Rv = __builtin_fmaf(av, Rv, dt_il * f);
        Rq = __builtin_fmaf(av, Rq, kq * t1);
        zr[j] = f;                                          // save f_j for P3
        const float s2 = __builtin_fmaf(as_, s,
                         __builtin_fmaf(dtn, zf,
                         __builtin_fmaf(-dtm, f, dtm)));
        f = __builtin_fmaf(DT, s, f);
        s = s2;
    }

    // ---------------- scan2: scalar weights av^(25*2^j) ----------------
    sA[tid] = Rv; sB[tid] = Rq;
    __syncthreads();
#pragma unroll
    for (int j = 0; j < LEVELS; ++j) {
        const int off = 1 << j;
        float nv = 0.0f, nq = 0.0f;
        const bool has = (cc >= off);
        if (has) { nv = sA[tid - off * GSIMS]; nq = sB[tid - off * GSIMS]; }
        __syncthreads();
        if (has) {
            Rv = __builtin_fmaf(AVP[j], nv, Rv);
            Rq = __builtin_fmaf(AVP[j], nq, Rq);
            sA[tid] = Rv; sB[tid] = Rq;
        }
        __syncthreads();
    }
    float v = avc, q = avc;                 // v0 = q0 = 1
    if (cc > 0) { v += sA[tid - GSIMS]; q += sB[tid - GSIMS]; }

    // ---------------- P3: consume registered f, compute y, store ----------------
    float* op = out + cc * (CL * BATCH) + sim;
#pragma unroll
    for (int j = 0; j < CL; ++j) {
        const float fj   = zr[j];
        const float invf = __builtin_amdgcn_rcpf(fj);
        const float e2   = EXP2F(lc * invf);
        const float t1   = __builtin_fmaf(-fj, e2, fj);
        const float vn   = __builtin_fmaf(av, v, dt_il * fj);
        const float qn   = __builtin_fmaf(av, q, kq * t1);
        const float invv = __builtin_amdgcn_rcpf(vn);
        const float y = __builtin_fmaf(-c2, qn * invv,
                        __builtin_fmaf(-c3, vn,
                        __builtin_fmaf(-c1, qn, c0)));
        __builtin_nontemporal_store(y, &op[j * BATCH]);
        v = vn; q = qn;
    }
}

extern "C" void kernel_launch(void* const* d_in, const int* in_sizes, int n_in,
                              void* d_out, int out_size, void* d_ws, size_t ws_size,
                              hipStream_t stream) {
    const float* noise   = (const float*)d_in[0];
    const float* p_sigma = (const float*)d_in[1];
    const float* p_mu    = (const float*)d_in[2];
    const float* p_lamb  = (const float*)d_in[3];
    const float* p_beta  = (const float*)d_in[4];
    const float* p_psi   = (const float*)d_in[5];
    const float* p_phi   = (const float*)d_in[6];
    const float* p_chi   = (const float*)d_in[7];

    balloon_scan<<<BATCH / GSIMS, NTHREADS, 0, stream>>>(
        noise, p_sigma, p_mu, p_lamb, p_beta, p_psi, p_phi, p_chi,
        (float*)d_out);
}

// Round 3
// 141.337 us; speedup vs baseline: 1.1594x; 1.1594x over previous
//
#include <hip/hip_runtime.h>

// Balloon-Windkessel BOLD, explicit Euler, T=1000, B=16384.
// alpha==1 decouples the system: (s,f) is an affine scan with constant 2x2
// matrix A; v,q are affine scans with constant scalar av = 1-DT/lamb. Only
// E(f) is nonlinear (pointwise). Parallelize T:
//   40 chunks x 25 steps; block = 16 lanes x 2 sims x 40 chunks = 640 thr.
//   Each thread owns TWO independent sims (ILP=2: two independent
//   recurrence chains per lane double latency hiding without more waves).
//   P1: per-chunk (s,f) affine aggregate           (8B vector z loads)
//   scan1 (LDS, Hillis-Steele, A^(25*2^j), 6 lvls) -> chunk-start (s,f)
//   P2: replay chunk f_t, accumulate v,q aggregates (reload z, L3-hot)
//   scan2 (scalar av^(25*2^j))                     -> chunk-start (v,q)
//   P3: replay, compute y, NT store                 (reload z)
// Streaming replay (not register arrays): round-1 showed 25-deep register
// arrays get demoted by the allocator and expose phase-boundary latency;
// the L3 absorbs the re-reads. NT stores keep the 64 MB output from
// evicting noise in L3 between passes.
// NOTE: __builtin_nontemporal_* requires clang ext_vector types, NOT HIP's
// float2 class — hence the f2 typedef below.
// Chunk-power matrices computed once in f64 keep chunk-start rounding
// ~1e-6; P2/P3 replay f with IDENTICAL ops so v,q see one consistent f.

#define BATCH     16384
#define DT        0.01f
#define NOISE_AMP 0.01f
#define V0        0.02f
#define CHUNKS    40
#define CL        25          // 40 * 25 = 1000 steps
#define LANES     16          // lanes per chunk-row
#define GSIMS     (LANES * 2) // 32 sims per block (2 per thread)
#define NTHREADS  (CHUNKS * LANES)   // 640
#define LEVELS    6           // ceil(log2(40))

typedef float f2 __attribute__((ext_vector_type(2)));

#if __has_builtin(__builtin_amdgcn_exp2f)
#define EXP2F(x) __builtin_amdgcn_exp2f(x)
#else
#define EXP2F(x) exp2f(x)
#endif

__device__ __forceinline__ float uf(float x) {
    return __uint_as_float(__builtin_amdgcn_readfirstlane(__float_as_uint(x)));
}

struct D22 { double a, b, c, d; };
__device__ __forceinline__ D22 dmul(D22 x, D22 y) {
    D22 r;
    r.a = x.a * y.a + x.b * y.c;  r.b = x.a * y.b + x.b * y.d;
    r.c = x.c * y.a + x.d * y.c;  r.d = x.c * y.b + x.d * y.d;
    return r;
}

__global__ __launch_bounds__(NTHREADS, 5) void balloon_scan(
    const float* __restrict__ noise,
    const float* __restrict__ p_sigma,
    const float* __restrict__ p_mu,
    const float* __restrict__ p_lamb,
    const float* __restrict__ p_beta,
    const float* __restrict__ p_psi,
    const float* __restrict__ p_phi,
    const float* __restrict__ p_chi,
    float* __restrict__ out)
{
    const int tid = threadIdx.x;
    const int g   = tid & (LANES - 1);   // lane within chunk-row
    const int cc  = tid >> 4;            // chunk 0..39
    const int sim = blockIdx.x * GSIMS + 2 * g;   // this thread's sim pair

    const float sigma = uf(p_sigma[0]);
    const float mu    = uf(p_mu[0]);
    const float lamb  = uf(p_lamb[0]);
    const float beta  = uf(p_beta[0]);
    const float psi   = uf(p_psi[0]);
    const float phi   = uf(p_phi[0]);
    const float chi   = uf(p_chi[0]);

    // ---- uniform fp32 step constants (identical forms to the validated R2) ----
    const float as_   = 1.0f - DT * sigma;
    const float dtn   = DT * NOISE_AMP;
    const float dtm   = DT * mu;
    const float dt_il = uf((float)(0.01 / (double)lamb));
    const float av    = 1.0f - dt_il;
    const float kq    = uf(dt_il / beta);
    const float lc    = uf(log2f(1.0f - beta));
    const float c0 = V0 * (phi + psi + chi), c1 = V0 * phi, c2 = V0 * psi, c3 = V0 * chi;

    // ---- chunk-power weights in f64, once: A^(25*2^j), av^(25*2^j) ----
    D22 A; A.a = 1.0 - 0.01 * (double)sigma; A.b = -0.01 * (double)mu;
           A.c = 0.01;                       A.d = 1.0;
    D22 A2 = dmul(A, A), A4 = dmul(A2, A2), A8 = dmul(A4, A4);
    D22 A16 = dmul(A8, A8);
    D22 P = dmul(dmul(A16, A8), A);                 // A^25
    double avd = 1.0 - 0.01 / (double)lamb;
    double av2 = avd * avd, av4 = av2 * av2, av8 = av4 * av4;
    double av16 = av8 * av8;
    double ap = av16 * av8 * avd;                   // av^25

    float M11[LEVELS], M12[LEVELS], M21[LEVELS], M22[LEVELS], AVP[LEVELS];
#pragma unroll
    for (int j = 0; j < LEVELS; ++j) {
        M11[j] = uf((float)P.a); M12[j] = uf((float)P.b);
        M21[j] = uf((float)P.c); M22[j] = uf((float)P.d);
        AVP[j] = uf((float)ap);
        P = dmul(P, P); ap = ap * ap;
    }

    // homogeneous parts at this thread's chunk start: A^(25c)*(0,1), av^(25c)*1
    float ws = 0.0f, wf = 1.0f, avc = 1.0f;
#pragma unroll
    for (int j = 0; j < LEVELS; ++j) {
        if ((cc >> j) & 1) {
            float t = __builtin_fmaf(M11[j], ws, M12[j] * wf);
            wf = __builtin_fmaf(M21[j], ws, M22[j] * wf);
            ws = t;
            avc *= AVP[j];
        }
    }

    __shared__ f2 sA[NTHREADS];
    __shared__ f2 sB[NTHREADS];

    const float* zp = noise + cc * (CL * BATCH) + sim;

    // ---------------- P1: (s,f) chunk aggregates, both sims ----------------
    float rs0 = 0.0f, rf0 = 0.0f, rs1 = 0.0f, rf1 = 0.0f;
#pragma unroll 5
    for (int j = 0; j < CL; ++j) {
        const f2 z = *reinterpret_cast<const f2*>(zp + j * BATCH);
        {
            const float u = __builtin_fmaf(dtn, z.x, dtm);
            const float t = __builtin_fmaf(as_, rs0, __builtin_fmaf(-dtm, rf0, u));
            rf0 = __builtin_fmaf(DT, rs0, rf0);
            rs0 = t;
        }
        {
            const float u = __builtin_fmaf(dtn, z.y, dtm);
            const float t = __builtin_fmaf(as_, rs1, __builtin_fmaf(-dtm, rf1, u));
            rf1 = __builtin_fmaf(DT, rs1, rf1);
            rs1 = t;
        }
    }

    // ---------------- scan1: inclusive over chunks, matrix weights ----------------
    sA[tid] = (f2){rs0, rs1}; sB[tid] = (f2){rf0, rf1};
    __syncthreads();
#pragma unroll
    for (int j = 0; j < LEVELS; ++j) {
        const int off = 1 << j;
        f2 ns = (f2){0.0f, 0.0f}, nf = (f2){0.0f, 0.0f};
        const bool has = (cc >= off);
        if (has) { ns = sA[tid - off * LANES]; nf = sB[tid - off * LANES]; }
        __syncthreads();
        if (has) {
            rs0 = __builtin_fmaf(M11[j], ns.x, __builtin_fmaf(M12[j], nf.x, rs0));
            rf0 = __builtin_fmaf(M21[j], ns.x, __builtin_fmaf(M22[j], nf.x, rf0));
            rs1 = __builtin_fmaf(M11[j], ns.y, __builtin_fmaf(M12[j], nf.y, rs1));
            rf1 = __builtin_fmaf(M21[j], ns.y, __builtin_fmaf(M22[j], nf.y, rf1));
            sA[tid] = (f2){rs0, rs1}; sB[tid] = (f2){rf0, rf1};
        }
        __syncthreads();
    }
    float s00 = ws, f00 = wf, s01 = ws, f01 = wf;
    if (cc > 0) {
        const f2 pa = sA[tid - LANES], pb = sB[tid - LANES];
        s00 += pa.x; f00 += pb.x;
        s01 += pa.y; f01 += pb.y;
    }
    __syncthreads();   // sA/sB reads done; safe to reuse for scan2

    // ---------------- P2: replay f, accumulate v,q aggregates ----------------
    float s0 = s00, f0 = f00, s1 = s01, f1 = f01;
    float Rv0 = 0.0f, Rq0 = 0.0f, Rv1 = 0.0f, Rq1 = 0.0f;
#pragma unroll 5
    for (int j = 0; j < CL; ++j) {
        const f2 z = *reinterpret_cast<const f2*>(zp + j * BATCH);
        {
            const float invf = __builtin_amdgcn_rcpf(f0);
            const float e2   = EXP2F(lc * invf);
            const float t1   = __builtin_fmaf(-f0, e2, f0);       // f*E(f)
            Rv0 = __builtin_fmaf(av, Rv0, dt_il * f0);
            Rq0 = __builtin_fmaf(av, Rq0, kq * t1);
            const float s2 = __builtin_fmaf(as_, s0,
                             __builtin_fmaf(dtn, z.x,
                             __builtin_fmaf(-dtm, f0, dtm)));
            f0 = __builtin_fmaf(DT, s0, f0);
            s0 = s2;
        }
        {
            const float invf = __builtin_amdgcn_rcpf(f1);
            const float e2   = EXP2F(lc * invf);
            const float t1   = __builtin_fmaf(-f1, e2, f1);
            Rv1 = __builtin_fmaf(av, Rv1, dt_il * f1);
            Rq1 = __builtin_fmaf(av, Rq1, kq * t1);
            const float s2 = __builtin_fmaf(as_, s1,
                             __builtin_fmaf(dtn, z.y,
                             __builtin_fmaf(-dtm, f1, dtm)));
            f1 = __builtin_fmaf(DT, s1, f1);
            s1 = s2;
        }
    }

    // ---------------- scan2: scalar weights av^(25*2^j) ----------------
    sA[tid] = (f2){Rv0, Rv1}; sB[tid] = (f2){Rq0, Rq1};
    __syncthreads();
#pragma unroll
    for (int j = 0; j < LEVELS; ++j) {
        const int off = 1 << j;
        f2 nv = (f2){0.0f, 0.0f}, nq = (f2){0.0f, 0.0f};
        const bool has = (cc >= off);
        if (has) { nv = sA[tid - off * LANES]; nq = sB[tid - off * LANES]; }
        __syncthreads();
        if (has) {
            Rv0 = __builtin_fmaf(AVP[j], nv.x, Rv0);
            Rq0 = __builtin_fmaf(AVP[j], nq.x, Rq0);
            Rv1 = __builtin_fmaf(AVP[j], nv.y, Rv1);
            Rq1 = __builtin_fmaf(AVP[j], nq.y, Rq1);
            sA[tid] = (f2){Rv0, Rv1}; sB[tid] = (f2){Rq0, Rq1};
        }
        __syncthreads();
    }
    float v0 = avc, q0 = avc, v1 = avc, q1 = avc;   // v_init = q_init = 1
    if (cc > 0) {
        const f2 pv = sA[tid - LANES], pq = sB[tid - LANES];
        v0 += pv.x; q0 += pq.x;
        v1 += pv.y; q1 += pq.y;
    }

    // ---------------- P3: replay, compute y, NT store ----------------
    s0 = s00; f0 = f00; s1 = s01; f1 = f01;
    float* op = out + cc * (CL * BATCH) + sim;
#pragma unroll 5
    for (int j = 0; j < CL; ++j) {
        const f2 z = *reinterpret_cast<const f2*>(zp + j * BATCH);
        f2 y;
        {
            const float invf = __builtin_amdgcn_rcpf(f0);
            const float e2   = EXP2F(lc * invf);
            const float t1   = __builtin_fmaf(-f0, e2, f0);
            const float vn   = __builtin_fmaf(av, v0, dt_il * f0);
            const float qn   = __builtin_fmaf(av, q0, kq * t1);
            const float s2 = __builtin_fmaf(as_, s0,
                             __builtin_fmaf(dtn, z.x,
                             __builtin_fmaf(-dtm, f0, dtm)));
            f0 = __builtin_fmaf(DT, s0, f0);
            s0 = s2;
            const float invv = __builtin_amdgcn_rcpf(vn);
            y.x = __builtin_fmaf(-c2, qn * invv,
                  __builtin_fmaf(-c3, vn,
                  __builtin_fmaf(-c1, qn, c0)));
            v0 = vn; q0 = qn;
        }
        {
            const float invf = __builtin_amdgcn_rcpf(f1);
            const float e2   = EXP2F(lc * invf);
            const float t1   = __builtin_fmaf(-f1, e2, f1);
            const float vn   = __builtin_fmaf(av, v1, dt_il * f1);
            const float qn   = __builtin_fmaf(av, q1, kq * t1);
            const float s2 = __builtin_fmaf(as_, s1,
                             __builtin_fmaf(dtn, z.y,
                             __builtin_fmaf(-dtm, f1, dtm)));
            f1 = __builtin_fmaf(DT, s1, f1);
            s1 = s2;
            const float invv = __builtin_amdgcn_rcpf(vn);
            y.y = __builtin_fmaf(-c2, qn * invv,
                  __builtin_fmaf(-c3, vn,
                  __builtin_fmaf(-c1, qn, c0)));
            v1 = vn; q1 = qn;
        }
        __builtin_nontemporal_store(y, reinterpret_cast<f2*>(op + j * BATCH));
    }
}

extern "C" void kernel_launch(void* const* d_in, const int* in_sizes, int n_in,
                              void* d_out, int out_size, void* d_ws, size_t ws_size,
                              hipStream_t stream) {
    const float* noise   = (const float*)d_in[0];
    const float* p_sigma = (const float*)d_in[1];
    const float* p_mu    = (const float*)d_in[2];
    const float* p_lamb  = (const float*)d_in[3];
    const float* p_beta  = (const float*)d_in[4];
    const float* p_psi   = (const float*)d_in[5];
    const float* p_phi   = (const float*)d_in[6];
    const float* p_chi   = (const float*)d_in[7];

    balloon_scan<<<BATCH / GSIMS, NTHREADS, 0, stream>>>(
        noise, p_sigma, p_mu, p_lamb, p_beta, p_psi, p_phi, p_chi,
        (float*)d_out);
}